// Round 6
// baseline (83.045 us; speedup 1.0000x reference)
//
#include <hip/hip_runtime.h>
#include <hip/hip_bf16.h>

#define KT 576   // CIN*9, GEMM k-order k' = (p*3+q)*64 + c

typedef __attribute__((ext_vector_type(8))) short  short8;
typedef __attribute__((ext_vector_type(4))) float  f32x4;

__device__ __forceinline__ unsigned short f2bf(float f) {
  union { float f; unsigned int u; } v; v.f = f;
  return (unsigned short)((v.u + 0x7FFFu + ((v.u >> 16) & 1u)) >> 16);  // RNE
}

// ---------------------------------------------------------------------------
// Pre-pass: xC2 bf16, layout [hp 34][wp 34][bb 8][cs 8][bl 16][cl 8]
// (= padded x with 16b x 8c micro-blocks contiguous). An MFMA A-fragment read
// (lane l15 -> bl, lg -> cs) is then one fully-coalesced 1KB wave load.
// ---------------------------------------------------------------------------
__global__ __launch_bounds__(256) void xC2_kernel(const float* __restrict__ x,
                                                  unsigned short* __restrict__ xC2) {
  const int hp = blockIdx.x, bb = blockIdx.y, t = threadIdx.x;
  __shared__ unsigned short tile[32 * 1024];   // [w 32][cs 8][bl 16][cl 8]
  const bool interior = (hp >= 1 && hp <= 32);
  if (interior) {
#pragma unroll 4
    for (int i = 0; i < 32; ++i) {
      const int row = i * 32 + (t >> 3);       // = bl*64 + c
      const int bl = row >> 6, c = row & 63;
      const int k = t & 7;                     // 16B chunk within 128B w-row
      const float4 v = *(const float4*)(x + ((size_t)(bb * 16 + bl) * 64 + c) * 1024 +
                                        (hp - 1) * 32 + k * 4);
      const int base = (k * 4) * 1024 + (c >> 3) * 128 + bl * 8 + (c & 7);
      tile[base]        = f2bf(v.x);
      tile[base + 1024] = f2bf(v.y);
      tile[base + 2048] = f2bf(v.z);
      tile[base + 3072] = f2bf(v.w);
    }
  }
  __syncthreads();
  unsigned short* dst = xC2 + (size_t)hp * 278528 + (size_t)bb * 1024;
  const uint4 z = make_uint4(0u, 0u, 0u, 0u);
  for (int idx = t; idx < 34 * 128; idx += 256) {
    const int wp = idx >> 7, s = idx & 127;
    uint4 v = z;
    if (interior && wp >= 1 && wp <= 32) v = *(const uint4*)&tile[(wp - 1) * 1024 + s * 8];
    *(uint4*)(dst + (size_t)wp * 8192 + s * 8) = v;
  }
}

// ---------------------------------------------------------------------------
// Main: grid 2048 = 1024 (h,w) x 2 d-halves; 4 waves, wave wv owns b-range
// [wv*32, wv*32+32). W staged once into k'-ordered XOR-swizzled LDS, loaded
// in 2 batches of 9 dwordx4 pinned by sched_barrier (9-deep VMEM ILP).
// Barrier-free k-loop: A prefetched one 3-step group ahead (coalesced 1KB
// wave loads from xC2); 2 ds_read_b128 + 4 MFMA per step. Direct scattered
// epilogue stores (L2 merges them: round-1 WRITE_SIZE == out size).
// ---------------------------------------------------------------------------
__global__ __launch_bounds__(256, 4) void lc_main(const float* __restrict__ Wt,
                                                  const float* __restrict__ bias,
                                                  const unsigned short* __restrict__ xC2,
                                                  float* __restrict__ out) {
  __shared__ unsigned short Wl[32 * KT];   // 36864 B
  __shared__ float blds[32];

  const int bid = (int)blockIdx.x;
  const int swz = (bid & 7) * 256 + (bid >> 3);   // XCD-contiguous ranges
  const int hw = swz >> 1, half = swz & 1;
  const int h = hw >> 5, w = hw & 31;
  const int t = threadIdx.x, lane = t & 63, wv = t >> 6;
  const int l15 = lane & 15, lg = lane >> 4;

  if (t < 32) blds[t] = bias[(half * 32 + t) * 1024 + hw];

  // ---- W staging: 2 batches x 9 coalesced dwordx4; loads pinned BEFORE the
  // convert/scatter by sched_barrier so all 9 are in flight together.
  const float* Wsrc = Wt + (size_t)hw * (64 * KT) + (size_t)half * (32 * KT);
#pragma unroll
  for (int bat = 0; bat < 2; ++bat) {
    float4 wreg[9];
#pragma unroll
    for (int i = 0; i < 9; ++i)
      wreg[i] = ((const float4*)Wsrc)[(bat * 9 + i) * 256 + t];
    __builtin_amdgcn_sched_barrier(0);   // keep all 9 loads issued first
#pragma unroll
    for (int i = 0; i < 9; ++i) {
      const int f = ((bat * 9 + i) * 256 + t) * 4;        // flat elem
      const int d = (((unsigned)(f >> 6)) * 7282u) >> 16; // f/576
      int kn = f - d * 576;
      int c = ((unsigned)kn * 7282u) >> 16;               // kn/9
      int r = kn - c * 9;                                 // r = p*3+q
      const float vv[4] = {wreg[i].x, wreg[i].y, wreg[i].z, wreg[i].w};
#pragma unroll
      for (int j = 0; j < 4; ++j) {
        const int kp = r * 64 + c;                        // k'
        const int slot = (kp >> 3) ^ (d & 7);             // XOR-swizzled slot
        Wl[d * KT + slot * 8 + (kp & 7)] = f2bf(vv[j]);
        if (++r == 9) { r = 0; ++c; }
      }
    }
  }
  __syncthreads();

  // lane-constant part of the A address: cs=lg, bl=l15; wave picks bb=wv*2(+bt)
  const unsigned short* xA = xC2 + (size_t)wv * 2048 + lg * 128 + l15 * 8;

  f32x4 acc[2][2];
#pragma unroll
  for (int bt = 0; bt < 2; ++bt)
#pragma unroll
    for (int dt = 0; dt < 2; ++dt) acc[bt][dt] = (f32x4){0.f, 0.f, 0.f, 0.f};

  const int x7 = l15 & 7;
  const int wrow0 = l15 * KT;
  const int wrow1 = (16 + l15) * KT;

  short8 A0[2][3], A1[2][3];
#pragma unroll
  for (int s = 0; s < 3; ++s) {                    // prologue: group 0
    const int pq = s >> 1, p = pq / 3, q = pq - p * 3;
    const size_t off = (size_t)(h + p) * 278528 + (size_t)(w + q) * 8192 + (s & 1) * 512;
    A0[0][s] = *(const short8*)(xA + off);
    A1[0][s] = *(const short8*)(xA + off + 1024);
  }
#pragma unroll
  for (int g = 0; g < 6; ++g) {
    const int cur = g & 1;
    if (g < 5) {                                   // prefetch group g+1
#pragma unroll
      for (int s = 0; s < 3; ++s) {
        const int step = (g + 1) * 3 + s;
        const int pq = step >> 1, p = pq / 3, q = pq - p * 3;
        const size_t off = (size_t)(h + p) * 278528 + (size_t)(w + q) * 8192 + (step & 1) * 512;
        A0[cur ^ 1][s] = *(const short8*)(xA + off);
        A1[cur ^ 1][s] = *(const short8*)(xA + off + 1024);
      }
    }
#pragma unroll
    for (int s = 0; s < 3; ++s) {                  // compute group g
      const int step = g * 3 + s;
      const int sb = step * 4 + lg;
      const short8 b0 = *(const short8*)&Wl[wrow0 + ((sb ^ x7) << 3)];
      const short8 b1 = *(const short8*)&Wl[wrow1 + ((sb ^ x7) << 3)];
      acc[0][0] = __builtin_amdgcn_mfma_f32_16x16x32_bf16(A0[cur][s], b0, acc[0][0], 0, 0, 0);
      acc[1][0] = __builtin_amdgcn_mfma_f32_16x16x32_bf16(A1[cur][s], b0, acc[1][0], 0, 0, 0);
      acc[0][1] = __builtin_amdgcn_mfma_f32_16x16x32_bf16(A0[cur][s], b1, acc[0][1], 0, 0, 0);
      acc[1][1] = __builtin_amdgcn_mfma_f32_16x16x32_bf16(A1[cur][s], b1, acc[1][1], 0, 0, 0);
    }
  }

  // epilogue: D col = lane&15 (d), row = lg*4+i (b); direct stores, L2 merges
#pragma unroll
  for (int dt = 0; dt < 2; ++dt) {
    const int dg = half * 32 + dt * 16 + l15;
    const float bv = blds[dt * 16 + l15];
#pragma unroll
    for (int bt = 0; bt < 2; ++bt) {
#pragma unroll
      for (int i = 0; i < 4; ++i) {
        const int b = wv * 32 + bt * 16 + lg * 4 + i;
        out[(size_t)b * 65536 + (size_t)dg * 1024 + hw] = acc[bt][dt][i] + bv;
      }
    }
  }
}

extern "C" void kernel_launch(void* const* d_in, const int* in_sizes, int n_in,
                              void* d_out, int out_size, void* d_ws, size_t ws_size,
                              hipStream_t stream) {
  const float* x    = (const float*)d_in[0];
  const float* wt   = (const float*)d_in[1];
  const float* bias = (const float*)d_in[2];
  float* out        = (float*)d_out;
  unsigned short* xC2 = (unsigned short*)d_ws;   // 18,939,904 B

  xC2_kernel<<<dim3(34, 8), 256, 0, stream>>>(x, xC2);
  lc_main<<<2048, 256, 0, stream>>>(wt, bias, xC2, out);
}

// Round 7
// 72.560 us; speedup vs baseline: 1.1445x; 1.1445x over previous
//
#include <hip/hip_runtime.h>
#include <hip/hip_bf16.h>

#define KT 576   // CIN*9, GEMM k-order k' = (p*3+q)*64 + c

typedef __attribute__((ext_vector_type(8))) short  short8;
typedef __attribute__((ext_vector_type(4))) float  f32x4;

__device__ __forceinline__ unsigned short f2bf(float f) {
  union { float f; unsigned int u; } v; v.f = f;
  return (unsigned short)((v.u + 0x7FFFu + ((v.u >> 16) & 1u)) >> 16);  // RNE
}

// ---------------------------------------------------------------------------
// Pre-pass: xC2 bf16, layout [hp 34][wp 34][bb 8][cs 8][bl 16][cl 8]
// (= padded x with 16b x 8c micro-blocks contiguous). An MFMA A-fragment read
// (lane l15 -> bl, lg -> cs) is then one fully-coalesced 1KB wave load.
// ---------------------------------------------------------------------------
__global__ __launch_bounds__(256) void xC2_kernel(const float* __restrict__ x,
                                                  unsigned short* __restrict__ xC2) {
  const int hp = blockIdx.x, bb = blockIdx.y, t = threadIdx.x;
  __shared__ unsigned short tile[32 * 1024];   // [w 32][cs 8][bl 16][cl 8]
  const bool interior = (hp >= 1 && hp <= 32);
  if (interior) {
#pragma unroll 4
    for (int i = 0; i < 32; ++i) {
      const int row = i * 32 + (t >> 3);       // = bl*64 + c
      const int bl = row >> 6, c = row & 63;
      const int k = t & 7;                     // 16B chunk within 128B w-row
      const float4 v = *(const float4*)(x + ((size_t)(bb * 16 + bl) * 64 + c) * 1024 +
                                        (hp - 1) * 32 + k * 4);
      const int base = (k * 4) * 1024 + (c >> 3) * 128 + bl * 8 + (c & 7);
      tile[base]        = f2bf(v.x);
      tile[base + 1024] = f2bf(v.y);
      tile[base + 2048] = f2bf(v.z);
      tile[base + 3072] = f2bf(v.w);
    }
  }
  __syncthreads();
  unsigned short* dst = xC2 + (size_t)hp * 278528 + (size_t)bb * 1024;
  const uint4 z = make_uint4(0u, 0u, 0u, 0u);
  for (int idx = t; idx < 34 * 128; idx += 256) {
    const int wp = idx >> 7, s = idx & 127;
    uint4 v = z;
    if (interior && wp >= 1 && wp <= 32) v = *(const uint4*)&tile[(wp - 1) * 1024 + s * 8];
    *(uint4*)(dst + (size_t)wp * 8192 + s * 8) = v;
  }
}

// ---------------------------------------------------------------------------
// Main: grid 2048 = 1024 (h,w) x 2 d-halves; 4 waves, wave wv owns b-range
// [wv*32, wv*32+32). W staged once into k'-ordered XOR-swizzled LDS via
// inline-asm global_load_dwordx4 batches (forced 9-deep VMEM ILP). k-loop is
// barrier-free with counted-vmcnt A double-buffer (issue 6, vmcnt(6), fence,
// compute 3 steps = 6 ds_read_b128 + 12 MFMA). Coalesced tmp epilogue.
// ---------------------------------------------------------------------------
__global__ __launch_bounds__(256, 4) void lc_main(const float* __restrict__ Wt,
                                                  const float* __restrict__ bias,
                                                  const unsigned short* __restrict__ xC2,
                                                  float* __restrict__ out,
                                                  float* __restrict__ tmp,
                                                  int useTmp) {
  __shared__ unsigned short Wl[32 * KT];   // 36864 B
  __shared__ float blds[32];

  const int bid = (int)blockIdx.x;
  const int swz = (bid & 7) * 256 + (bid >> 3);   // XCD-contiguous ranges
  const int hw = swz >> 1, half = swz & 1;
  const int h = hw >> 5, w = hw & 31;
  const int t = threadIdx.x, lane = t & 63, wv = t >> 6;
  const int l15 = lane & 15, lg = lane >> 4;

  if (t < 32) blds[t] = bias[(half * 32 + t) * 1024 + hw];

  const float* Wsrc = Wt + (size_t)hw * (64 * KT) + (size_t)half * (32 * KT);
  const unsigned short* xA = xC2 + (size_t)wv * 2048 + lg * 128 + l15 * 8;

  short8 A0[2][3], A1[2][3];
  f32x4 acc[2][2];
#pragma unroll
  for (int bt = 0; bt < 2; ++bt)
#pragma unroll
    for (int dt = 0; dt < 2; ++dt) acc[bt][dt] = (f32x4){0.f, 0.f, 0.f, 0.f};

  // ---- W staging: 2 batches x 9 asm loads (forced in-flight), then scatter.
#pragma unroll
  for (int bat = 0; bat < 2; ++bat) {
    float4 wreg[9];
#pragma unroll
    for (int i = 0; i < 9; ++i) {
      const float4* p = (const float4*)Wsrc + ((bat * 9 + i) * 256 + t);
      asm volatile("global_load_dwordx4 %0, %1, off" : "=v"(wreg[i]) : "v"(p));
    }
    if (bat == 1) {  // hide A-prologue latency under batch-2 drain
#pragma unroll
      for (int s = 0; s < 3; ++s) {
        const int pq = s >> 1, p = pq / 3, q = pq - p * 3;
        const size_t off = (size_t)(h + p) * 278528 + (size_t)(w + q) * 8192 + (s & 1) * 512;
        const short8* p0 = (const short8*)(xA + off);
        const short8* p1 = (const short8*)(xA + off + 1024);
        asm volatile("global_load_dwordx4 %0, %1, off" : "=v"(A0[0][s]) : "v"(p0));
        asm volatile("global_load_dwordx4 %0, %1, off" : "=v"(A1[0][s]) : "v"(p1));
      }
    }
    asm volatile("s_waitcnt vmcnt(0)" ::: "memory");
    __builtin_amdgcn_sched_barrier(0);
#pragma unroll
    for (int i = 0; i < 9; ++i) {
      const int f = ((bat * 9 + i) * 256 + t) * 4;        // flat elem
      const int d = (((unsigned)(f >> 6)) * 7282u) >> 16; // f/576
      int kn = f - d * 576;
      int c = ((unsigned)kn * 7282u) >> 16;               // kn/9
      int r = kn - c * 9;                                 // r = p*3+q
      const float vv[4] = {wreg[i].x, wreg[i].y, wreg[i].z, wreg[i].w};
#pragma unroll
      for (int j = 0; j < 4; ++j) {
        const int kp = r * 64 + c;                        // k'
        const int slot = (kp >> 3) ^ (d & 7);             // XOR-swizzled slot
        Wl[d * KT + slot * 8 + (kp & 7)] = f2bf(vv[j]);
        if (++r == 9) { r = 0; ++c; }
      }
    }
  }
  __syncthreads();

  const int x7 = l15 & 7;
  const int wrow0 = l15 * KT;
  const int wrow1 = (16 + l15) * KT;

  // ---- k-loop: counted-vmcnt A double-buffer, 3 steps per group.
#pragma unroll
  for (int g = 0; g < 6; ++g) {
    const int cur = g & 1;
    if (g < 5) {
#pragma unroll
      for (int s = 0; s < 3; ++s) {
        const int step = (g + 1) * 3 + s;
        const int pq = step >> 1, p = pq / 3, q = pq - p * 3;
        const size_t off = (size_t)(h + p) * 278528 + (size_t)(w + q) * 8192 + (step & 1) * 512;
        const short8* p0 = (const short8*)(xA + off);
        const short8* p1 = (const short8*)(xA + off + 1024);
        asm volatile("global_load_dwordx4 %0, %1, off" : "=v"(A0[cur ^ 1][s]) : "v"(p0));
        asm volatile("global_load_dwordx4 %0, %1, off" : "=v"(A1[cur ^ 1][s]) : "v"(p1));
      }
      asm volatile("s_waitcnt vmcnt(6)" ::: "memory");
    } else {
      asm volatile("s_waitcnt vmcnt(0)" ::: "memory");
    }
    __builtin_amdgcn_sched_barrier(0);
#pragma unroll
    for (int s = 0; s < 3; ++s) {
      const int step = g * 3 + s;
      const int sb = step * 4 + lg;
      const short8 b0 = *(const short8*)&Wl[wrow0 + ((sb ^ x7) << 3)];
      const short8 b1 = *(const short8*)&Wl[wrow1 + ((sb ^ x7) << 3)];
      acc[0][0] = __builtin_amdgcn_mfma_f32_16x16x32_bf16(A0[cur][s], b0, acc[0][0], 0, 0, 0);
      acc[1][0] = __builtin_amdgcn_mfma_f32_16x16x32_bf16(A1[cur][s], b0, acc[1][0], 0, 0, 0);
      acc[0][1] = __builtin_amdgcn_mfma_f32_16x16x32_bf16(A0[cur][s], b1, acc[0][1], 0, 0, 0);
      acc[1][1] = __builtin_amdgcn_mfma_f32_16x16x32_bf16(A1[cur][s], b1, acc[1][1], 0, 0, 0);
    }
  }

  if (useTmp) {
    // coalesced: tmp[hw][half][dl 32][b 128], full 64B-line stores
    float* tb = tmp + (size_t)(hw * 2 + half) * (32 * 128) + wv * 32;
#pragma unroll
    for (int dt = 0; dt < 2; ++dt) {
      const float bv = blds[dt * 16 + l15];
#pragma unroll
      for (int bt = 0; bt < 2; ++bt) {
        f32x4 v = acc[bt][dt];
        v[0] += bv; v[1] += bv; v[2] += bv; v[3] += bv;
        *(f32x4*)(tb + (dt * 16 + l15) * 128 + bt * 16 + lg * 4) = v;
      }
    }
  } else {
    // fallback: scattered direct stores (D col = lane&15 (d), row = lg*4+i (b))
#pragma unroll
    for (int dt = 0; dt < 2; ++dt) {
      const int dg = half * 32 + dt * 16 + l15;
      const float bv = blds[dt * 16 + l15];
#pragma unroll
      for (int bt = 0; bt < 2; ++bt) {
#pragma unroll
        for (int i = 0; i < 4; ++i) {
          const int b = wv * 32 + bt * 16 + lg * 4 + i;
          out[(size_t)b * 65536 + (size_t)dg * 1024 + hw] = acc[bt][dt][i] + bv;
        }
      }
    }
  }
}

// ---------------------------------------------------------------------------
// tmp[hw][half][dl][b] -> out[b][d][hw], both sides coalesced via LDS tile.
// ---------------------------------------------------------------------------
__global__ __launch_bounds__(256) void tr_out(const float* __restrict__ tmp,
                                              float* __restrict__ out) {
  const int h = blockIdx.x;        // 0..31
  const int d = blockIdx.y;        // 0..63
  const int half = d >> 5, dl = d & 31;
  const int t = threadIdx.x;
  __shared__ float ls[32 * 132];   // [w][b+pad4]
  {
    const int w = t >> 3, bc = t & 7;
    const float* src = tmp + ((size_t)((h * 32 + w) * 2 + half) * 32 + dl) * 128 + bc * 16;
    float* dst = ls + w * 132 + bc * 16;
#pragma unroll
    for (int k = 0; k < 4; ++k) ((float4*)dst)[k] = ((const float4*)src)[k];
  }
  __syncthreads();
  {
    const int b = t >> 1, wh = t & 1;
    float4 o[4];
#pragma unroll
    for (int k = 0; k < 4; ++k)
#pragma unroll
      for (int j = 0; j < 4; ++j)
        ((float*)&o[k])[j] = ls[(wh * 16 + k * 4 + j) * 132 + b];
    float* dst = out + (size_t)b * 65536 + (size_t)d * 1024 + h * 32 + wh * 16;
#pragma unroll
    for (int k = 0; k < 4; ++k) ((float4*)dst)[k] = o[k];
  }
}

extern "C" void kernel_launch(void* const* d_in, const int* in_sizes, int n_in,
                              void* d_out, int out_size, void* d_ws, size_t ws_size,
                              hipStream_t stream) {
  const float* x    = (const float*)d_in[0];
  const float* wt   = (const float*)d_in[1];
  const float* bias = (const float*)d_in[2];
  float* out        = (float*)d_out;

  unsigned short* xC2 = (unsigned short*)d_ws;          // 18,939,904 B
  const size_t XC2_BYTES = 18939904u;
  const size_t TMP_BYTES = 33554432u;                   // 1024*2*32*128*4
  const int useTmp = (ws_size >= XC2_BYTES + TMP_BYTES) ? 1 : 0;
  float* tmp = (float*)((char*)d_ws + XC2_BYTES);

  xC2_kernel<<<dim3(34, 8), 256, 0, stream>>>(x, xC2);
  lc_main<<<2048, 256, 0, stream>>>(wt, bias, xC2, out, tmp, useTmp);
  if (useTmp) tr_out<<<dim3(32, 64), 256, 0, stream>>>(tmp, out);
}

// Round 9
// 68.538 us; speedup vs baseline: 1.2117x; 1.0587x over previous
//
#include <hip/hip_runtime.h>
#include <hip/hip_bf16.h>

#define KT 576   // CIN*9, GEMM k-order k' = (p*3+q)*64 + c

typedef __attribute__((ext_vector_type(8))) short  short8;
typedef __attribute__((ext_vector_type(4))) float  f32x4;

#define VMCNT(n) asm volatile("s_waitcnt vmcnt(" #n ")" ::: "memory")
#define SB() __builtin_amdgcn_sched_barrier(0)

__device__ __forceinline__ unsigned short f2bf(float f) {
  union { float f; unsigned int u; } v; v.f = f;
  return (unsigned short)((v.u + 0x7FFFu + ((v.u >> 16) & 1u)) >> 16);  // RNE
}

// ---------------------------------------------------------------------------
// Pre-pass: xC2 bf16, layout [hp 34][wp 34][bb 8][cs 8][bl 16][cl 8].
// ---------------------------------------------------------------------------
__global__ __launch_bounds__(256) void xC2_kernel(const float* __restrict__ x,
                                                  unsigned short* __restrict__ xC2) {
  const int hp = blockIdx.x, bb = blockIdx.y, t = threadIdx.x;
  __shared__ unsigned short tile[32 * 1024];   // [w 32][cs 8][bl 16][cl 8]
  const bool interior = (hp >= 1 && hp <= 32);
  if (interior) {
#pragma unroll 4
    for (int i = 0; i < 32; ++i) {
      const int row = i * 32 + (t >> 3);       // = bl*64 + c
      const int bl = row >> 6, c = row & 63;
      const int k = t & 7;
      const float4 v = *(const float4*)(x + ((size_t)(bb * 16 + bl) * 64 + c) * 1024 +
                                        (hp - 1) * 32 + k * 4);
      const int base = (k * 4) * 1024 + (c >> 3) * 128 + bl * 8 + (c & 7);
      tile[base]        = f2bf(v.x);
      tile[base + 1024] = f2bf(v.y);
      tile[base + 2048] = f2bf(v.z);
      tile[base + 3072] = f2bf(v.w);
    }
  }
  __syncthreads();
  unsigned short* dst = xC2 + (size_t)hp * 278528 + (size_t)bb * 1024;
  const uint4 z = make_uint4(0u, 0u, 0u, 0u);
  for (int idx = t; idx < 34 * 128; idx += 256) {
    const int wp = idx >> 7, s = idx & 127;
    uint4 v = z;
    if (interior && wp >= 1 && wp <= 32) v = *(const uint4*)&tile[(wp - 1) * 1024 + s * 8];
    *(uint4*)(dst + (size_t)wp * 8192 + s * 8) = v;
  }
}

// ---------------------------------------------------------------------------
// Main: 512 blocks = (h 32) x (wq 8) x (half 2). Each block: 4 chained
// mini-GEMMs (w = wq*4+j), M=128b x N=32d x K=576, W double-buffered in LDS
// (k'-ordered, XOR-swizzled), W(j+1) issued at gemm-j start, A 3-deep,
// all waits counted vmcnt. Schedule fully macro-expanded (literal j/g/N).
// launch_bounds(256,1): 512-VGPR budget so asm-defined regs never spill.
// ---------------------------------------------------------------------------
__global__ __launch_bounds__(256, 1) void lc_main(const float* __restrict__ Wt,
                                                  const float* __restrict__ bias,
                                                  const unsigned short* __restrict__ xC2,
                                                  float* __restrict__ out) {
  __shared__ unsigned short Wl[2][32 * KT];   // 2 x 36864 B
  __shared__ float blds[128];                 // [j 4][dl 32]

  const int bid = (int)blockIdx.x;
  const int swz = (bid & 7) * 64 + (bid >> 3);    // 64-block chunks per XCD
  const int h = swz >> 4, rem = swz & 15, wq = rem >> 1, half = rem & 1;
  const int t = threadIdx.x, lane = t & 63, wv = t >> 6;
  const int l15 = lane & 15, lg = lane >> 4;

  if (t < 128)
    blds[t] = bias[(half * 32 + (t & 31)) * 1024 + h * 32 + wq * 4 + (t >> 5)];

  const unsigned short* xA = xC2 + (size_t)wv * 2048 + lg * 128 + l15 * 8;
  const int x7 = l15 & 7;
  const int wrow0 = l15 * KT;
  const int wrow1 = (16 + l15) * KT;

  f32x4 acc[4][2][2];
#pragma unroll
  for (int j = 0; j < 4; ++j)
#pragma unroll
    for (int bt = 0; bt < 2; ++bt)
#pragma unroll
      for (int dt = 0; dt < 2; ++dt) acc[j][bt][dt] = (f32x4){0.f, 0.f, 0.f, 0.f};

  short8 As0[3][3], As1[3][3];   // A slots [(j*6+g)%3][s]
  float4 wreg[18];

#define ISSUE_W(jj)                                                           \
  {                                                                           \
    const float* ws = Wt + (size_t)(h * 32 + wq * 4 + (jj)) * (64 * KT) +     \
                      (size_t)half * (32 * KT);                               \
    _Pragma("unroll")                                                         \
    for (int i = 0; i < 18; ++i) {                                            \
      const float4* p = (const float4*)ws + (i * 256 + t);                    \
      asm volatile("global_load_dwordx4 %0, %1, off" : "=v"(wreg[i]) : "v"(p)); \
    }                                                                         \
  }

#define ISSUE_A(K)                                                            \
  {                                                                           \
    _Pragma("unroll")                                                         \
    for (int s = 0; s < 3; ++s) {                                             \
      const int step = ((K) % 6) * 3 + s;                                     \
      const int pq = step >> 1, p = pq / 3, q = pq - p * 3;                   \
      const size_t off = (size_t)(h + p) * 278528 +                           \
                         (size_t)(wq * 4 + (K) / 6 + q) * 8192 + (step & 1) * 512; \
      const short8* p0 = (const short8*)(xA + off);                           \
      const short8* p1 = (const short8*)(xA + off + 1024);                    \
      asm volatile("global_load_dwordx4 %0, %1, off" : "=v"(As0[(K) % 3][s]) : "v"(p0)); \
      asm volatile("global_load_dwordx4 %0, %1, off" : "=v"(As1[(K) % 3][s]) : "v"(p1)); \
    }                                                                         \
  }

#define SCATTER(buf)                                                          \
  {                                                                           \
    _Pragma("unroll")                                                         \
    for (int i = 0; i < 18; ++i) {                                            \
      const int f = (i * 256 + t) * 4;                                        \
      const int d = (((unsigned)(f >> 6)) * 7282u) >> 16;                     \
      int kn = f - d * 576;                                                   \
      int c = ((unsigned)kn * 7282u) >> 16;                                   \
      int r = kn - c * 9;                                                     \
      const float vv[4] = {wreg[i].x, wreg[i].y, wreg[i].z, wreg[i].w};       \
      _Pragma("unroll")                                                       \
      for (int jx = 0; jx < 4; ++jx) {                                        \
        const int kp = r * 64 + c;                                            \
        const int slot = (kp >> 3) ^ (d & 7);                                 \
        Wl[buf][d * KT + slot * 8 + (kp & 7)] = f2bf(vv[jx]);                 \
        if (++r == 9) { r = 0; ++c; }                                         \
      }                                                                       \
    }                                                                         \
  }

#define STEP(jj, gg, NN)                                                      \
  {                                                                           \
    VMCNT(NN);                                                                \
    SB();                                                                     \
    _Pragma("unroll")                                                         \
    for (int s = 0; s < 3; ++s) {                                             \
      const int sb = ((gg) * 3 + s) * 4 + lg;                                 \
      const short8 b0 = *(const short8*)&Wl[(jj) & 1][wrow0 + ((sb ^ x7) << 3)]; \
      const short8 b1 = *(const short8*)&Wl[(jj) & 1][wrow1 + ((sb ^ x7) << 3)]; \
      acc[(jj)][0][0] = __builtin_amdgcn_mfma_f32_16x16x32_bf16(As0[((jj) * 6 + (gg)) % 3][s], b0, acc[(jj)][0][0], 0, 0, 0); \
      acc[(jj)][1][0] = __builtin_amdgcn_mfma_f32_16x16x32_bf16(As1[((jj) * 6 + (gg)) % 3][s], b0, acc[(jj)][1][0], 0, 0, 0); \
      acc[(jj)][0][1] = __builtin_amdgcn_mfma_f32_16x16x32_bf16(As0[((jj) * 6 + (gg)) % 3][s], b1, acc[(jj)][0][1], 0, 0, 0); \
      acc[(jj)][1][1] = __builtin_amdgcn_mfma_f32_16x16x32_bf16(As1[((jj) * 6 + (gg)) % 3][s], b1, acc[(jj)][1][1], 0, 0, 0); \
    }                                                                         \
  }

  // ---- prologue: W0 + A(0..2); drain W0 (18 A younger), scatter buf0 ----
  ISSUE_W(0);
  ISSUE_A(0); ISSUE_A(1); ISSUE_A(2);
  VMCNT(18);
  SB();
  SCATTER(0);
  __syncthreads();

  // ---- j=0 (reads buf0, prefetches W1 -> buf1) ----
  ISSUE_W(1);
  STEP(0, 0, 30); ISSUE_A(3);
  STEP(0, 1, 30); ISSUE_A(4);
  STEP(0, 2, 30); ISSUE_A(5);
  STEP(0, 3, 12); ISSUE_A(6);    // vmcnt(12) also drains W1
  STEP(0, 4, 12); ISSUE_A(7);
  STEP(0, 5, 12); ISSUE_A(8);
  SCATTER(1);
  __syncthreads();

  // ---- j=1 ----
  ISSUE_W(2);
  STEP(1, 0, 30); ISSUE_A(9);
  STEP(1, 1, 30); ISSUE_A(10);
  STEP(1, 2, 30); ISSUE_A(11);
  STEP(1, 3, 12); ISSUE_A(12);
  STEP(1, 4, 12); ISSUE_A(13);
  STEP(1, 5, 12); ISSUE_A(14);
  SCATTER(0);
  __syncthreads();

  // ---- j=2 ----
  ISSUE_W(3);
  STEP(2, 0, 30); ISSUE_A(15);
  STEP(2, 1, 30); ISSUE_A(16);
  STEP(2, 2, 30); ISSUE_A(17);
  STEP(2, 3, 12); ISSUE_A(18);
  STEP(2, 4, 12); ISSUE_A(19);
  STEP(2, 5, 12); ISSUE_A(20);
  SCATTER(1);
  __syncthreads();

  // ---- j=3 (no W prefetch) ----
  STEP(3, 0, 12); ISSUE_A(21);
  STEP(3, 1, 12); ISSUE_A(22);
  STEP(3, 2, 12); ISSUE_A(23);
  STEP(3, 3, 12);
  STEP(3, 4, 6);
  STEP(3, 5, 0);

  // ---- epilogue: float4 over the 4 consecutive w; 16B coalesced stores ----
#pragma unroll
  for (int dt = 0; dt < 2; ++dt) {
    const int dd = dt * 16 + l15;
    const int dg = half * 32 + dd;
    const float bv0 = blds[dd], bv1 = blds[32 + dd], bv2 = blds[64 + dd], bv3 = blds[96 + dd];
#pragma unroll
    for (int bt = 0; bt < 2; ++bt) {
#pragma unroll
      for (int i = 0; i < 4; ++i) {
        const int b = wv * 32 + bt * 16 + lg * 4 + i;
        float4 v;
        v.x = acc[0][bt][dt][i] + bv0;
        v.y = acc[1][bt][dt][i] + bv1;
        v.z = acc[2][bt][dt][i] + bv2;
        v.w = acc[3][bt][dt][i] + bv3;
        *(float4*)(out + (size_t)b * 65536 + (size_t)dg * 1024 + h * 32 + wq * 4) = v;
      }
    }
  }
}

extern "C" void kernel_launch(void* const* d_in, const int* in_sizes, int n_in,
                              void* d_out, int out_size, void* d_ws, size_t ws_size,
                              hipStream_t stream) {
  const float* x    = (const float*)d_in[0];
  const float* wt   = (const float*)d_in[1];
  const float* bias = (const float*)d_in[2];
  float* out        = (float*)d_out;
  unsigned short* xC2 = (unsigned short*)d_ws;   // 18,939,904 B

  xC2_kernel<<<dim3(34, 8), 256, 0, stream>>>(x, xC2);
  lc_main<<<512, 256, 0, stream>>>(wt, bias, xC2, out);
}